// Round 2
// baseline (15429.918 us; speedup 1.0000x reference)
//
#include <hip/hip_runtime.h>
#include <hip/hip_bf16.h>

#define B_   32
#define T_   512
#define H_   1024
#define L_   256
#define V_   13
#define G4H  4096
#define KHL  1280   // H + L

typedef float f32x4 __attribute__((ext_vector_type(4)));
typedef short s16x8 __attribute__((ext_vector_type(8)));
typedef unsigned short u16;
typedef unsigned int   u32;

// ---------------- ws layout (bytes) ----------------
// Ax  : u16 [1026][16384]    @ 0           (33,619,968)  h chain in MFMA A-frag
//                                           layout; slab id = s*2+mt, s in [0,513)
// Bf  : u16 [4,194,304]      @ 33,619,968  (8,388,608)   W_hh MFMA B-fragments
// Bf2 : u16 [1,310,720]      @ 42,008,576  (2,621,440)   Wnl  MFMA B-fragments
// bias: f32 [4096]           @ 44,630,016  (16,384)      b_ih + b_hh
// Az  : u16 [2][4096]        @ 44,646,400  (16,384)      latent in A-frag layout
// bar : int [64]             @ 44,662,784  (256)         grid barrier (cnt@0, sense@32)
// mid : u16 [16384][1024]    @ 44,663,040  (33,554,432)  relu(feat@Wnl^T+bnl)
// total ~78.2 MB
#define OFF_BF   33619968u
#define OFF_BF2  42008576u
#define OFF_BIAS 44630016u
#define OFF_AZ   44646400u
#define OFF_BAR  44662784u
#define OFF_MID  44663040u

__device__ __forceinline__ u16 f2bf(float f) {
    union { float f; u32 u; } v; v.f = f;
    u32 u = v.u;
    u32 r = (u + 0x7fffu + ((u >> 16) & 1u)) >> 16;   // RNE
    return (u16)r;
}
__device__ __forceinline__ float bf2f(u16 h) {
    union { u32 u; float f; } v; v.u = ((u32)h) << 16;
    return v.f;
}
__device__ __forceinline__ float sigm_(float x) {
    x = fminf(fmaxf(x, -30.f), 30.f);
    return 1.f / (1.f + __expf(-x));
}
__device__ __forceinline__ float tanh_(float x) {
    x = fminf(fmaxf(x, -15.f), 15.f);
    float e = __expf(2.f * x);
    return (e - 1.f) / (e + 1.f);
}

// A-fragment position of element (b_local in [0,16), k) within a 16384-u16 slab:
// idx = (k>>5)*512 + (b_local | (((k>>3)&3)<<4))*8 + (k&7)
__device__ __forceinline__ u32 afrag_pos(int bl, int k) {
    return (u32)((k >> 5) * 512 + ((bl | (((k >> 3) & 3) << 4)) << 3) + (k & 7));
}

// ---------------------------------------------------------------------------
// init: h0 = relu(latent @ Wz^T + bz) -> Ax[0] frag layout; bias; Az; barrier
__global__ __launch_bounds__(256) void k_init_misc(
        const float* __restrict__ latent, const float* __restrict__ Wz,
        const float* __restrict__ bz, const float* __restrict__ b_ih,
        const float* __restrict__ b_hh,
        u16* __restrict__ Ax, float* __restrict__ bias,
        u16* __restrict__ Az, int* __restrict__ bar) {
    int gid = blockIdx.x * 256 + threadIdx.x;          // [0, 32768)
    int b = gid >> 10, j = gid & 1023;
    const float* lrow = latent + b * L_;
    const float* wrow = Wz + j * L_;
    float acc = bz[j];
    #pragma unroll 4
    for (int l = 0; l < L_; ++l) acc += lrow[l] * wrow[l];
    Ax[(b >> 4) * 16384 + afrag_pos(b & 15, j)] = f2bf(fmaxf(acc, 0.f));
    if (gid < G4H) bias[gid] = b_ih[gid] + b_hh[gid];
    if (gid < B_ * L_) {
        int bb = gid >> 8, l = gid & 255;
        Az[(bb >> 4) * 4096 + afrag_pos(bb & 15, l)] = f2bf(latent[gid]);
    }
    if (gid == 0) { bar[0] = 0; bar[32] = 0; }
}

// W_hh -> MFMA B fragments, column-interleaved so one 16-wide N-tile holds
// all 4 gates for 4 consecutive j. idx = (nt<<14)|(kc<<9)|(lane<<3)|jv
__global__ __launch_bounds__(256) void k_init_wfrag(
        const float* __restrict__ W_hh, u16* __restrict__ Bf) {
    int base = blockIdx.x * 256 + threadIdx.x;         // 2048 blocks
    #pragma unroll
    for (int i = 0; i < 8; ++i) {
        int idx = base + i * 524288;                   // [0, 4194304)
        int jv   = idx & 7;
        int lane = (idx >> 3) & 63;
        int kc   = (idx >> 9) & 31;
        int nt   = idx >> 14;
        int u = lane & 15;
        int row = (u >> 2) * H_ + nt * 4 + (u & 3);
        int k = kc * 32 + (lane >> 4) * 8 + jv;
        Bf[idx] = f2bf(W_hh[row * H_ + k]);
    }
}

// Wnl -> MFMA B fragments: idx = ((nt2*40+kc)<<9)|(lane<<3)|jv
__global__ __launch_bounds__(256) void k_init_wfrag2(
        const float* __restrict__ Wnl, u16* __restrict__ Bf2) {
    int idx = blockIdx.x * 256 + threadIdx.x;
    for (; idx < 1310720; idx += 524288) {
        int jv   = idx & 7;
        int lane = (idx >> 3) & 63;
        int q    = idx >> 9;                           // nt2*40 + kc
        int kc   = q % 40;
        int nt2  = q / 40;
        int n = nt2 * 16 + (lane & 15);
        int k = kc * 32 + (lane >> 4) * 8 + jv;
        Bf2[idx] = f2bf(Wnl[n * KHL + k]);
    }
}

// ---------------------------------------------------------------------------
// Persistent LSTM recurrence: 256 blocks x 128 thr (2 waves). One grid barrier
// per step. Block: mt = bid&1 (16 b's), waves cover nt = (bid>>1)*2 + w.
// W_hh B-frags + W_ih rows + bias + c state all in registers.
__global__ __launch_bounds__(128, 1) void k_recur(
        const float* __restrict__ seq, const float* __restrict__ W_ih,
        const float* __restrict__ bias, const u16* __restrict__ Bf,
        u16* __restrict__ Ax, int* __restrict__ bar) {
    __shared__ u16 Ah[16384];             // A-frag slab for (s, mt), 32 KB
    __shared__ float scr[2][16][17];      // [wave][u][b_local]
    int tid = threadIdx.x;
    int bid = blockIdx.x;
    int mt = bid & 1;
    int w = tid >> 6, L = tid & 63;
    int nt = (bid >> 1) * 2 + w;          // [0,256)
    int lm = L & 15, quad = L >> 4;

    // one-time: B-fragments into registers (128 VGPR)
    s16x8 bfr[32];
    {
        const u16* bfp = Bf + (size_t)nt * 16384 + L * 8;
        #pragma unroll
        for (int kc = 0; kc < 32; ++kc)
            bfr[kc] = *reinterpret_cast<const s16x8*>(bfp + kc * 512);
    }
    // one-time: W_ih rows + bias for this lane's (jj = quad) output columns
    int jj = quad;
    int jg = nt * 4 + jj;
    int b = mt * 16 + lm;
    float wih[4][V_], bsv[4];
    #pragma unroll
    for (int gg = 0; gg < 4; ++gg) {
        const float* wr = W_ih + (size_t)(gg * H_ + jg) * V_;
        #pragma unroll
        for (int v = 0; v < V_; ++v) wih[gg][v] = wr[v];
        bsv[gg] = bias[gg * H_ + jg];
    }
    const float* xcol = seq + (size_t)b * (T_ * V_);
    // h-write position within destination slab (loop-invariant)
    u32 hpos = (u32)((nt >> 3) * 512 + ((lm | (((nt >> 1) & 3) << 4)) << 3)
                     + ((nt & 1) * 4 + jj));
    float c = 0.f;

    for (int s = 0; s < T_; ++s) {
        // stage A slab (contiguous 32 KB) into LDS
        const u16* src = Ax + ((size_t)s * 2 + mt) * 16384;
        #pragma unroll
        for (int it = 0; it < 16; ++it) {
            int idx = it * 128 + tid;
            *reinterpret_cast<uint4*>(&Ah[idx * 8]) =
                *reinterpret_cast<const uint4*>(src + idx * 8);
        }
        __syncthreads();

        // MFMA: gates tile (16 b x 16 cols), K=1024, two independent acc chains
        f32x4 acc0 = {0.f, 0.f, 0.f, 0.f}, acc1 = {0.f, 0.f, 0.f, 0.f};
        const u16* ap = Ah + L * 8;
        #pragma unroll
        for (int kc = 0; kc < 32; kc += 2) {
            s16x8 a0 = *reinterpret_cast<const s16x8*>(ap + kc * 512);
            s16x8 a1 = *reinterpret_cast<const s16x8*>(ap + kc * 512 + 512);
            acc0 = __builtin_amdgcn_mfma_f32_16x16x32_bf16(a0, bfr[kc], acc0, 0, 0, 0);
            acc1 = __builtin_amdgcn_mfma_f32_16x16x32_bf16(a1, bfr[kc + 1], acc1, 0, 0, 0);
        }
        #pragma unroll
        for (int r = 0; r < 4; ++r) scr[w][lm][quad * 4 + r] = acc0[r] + acc1[r];
        __syncthreads();

        // update for (b, jg): gather 4 gates, add x@W_ih^T + bias, nonlinearity
        const float* xrow = xcol + s * V_;
        float xv[V_];
        #pragma unroll
        for (int v = 0; v < V_; ++v) xv[v] = xrow[v];
        float g[4];
        #pragma unroll
        for (int gg = 0; gg < 4; ++gg) {
            float a = scr[w][gg * 4 + jj][lm] + bsv[gg];
            #pragma unroll
            for (int v = 0; v < V_; ++v) a += xv[v] * wih[gg][v];
            g[gg] = a;
        }
        float ig = sigm_(g[0]), fg = sigm_(g[1]);
        float gt = tanh_(g[2]), og = sigm_(g[3]);
        c = fg * c + ig * gt;
        float hv = og * tanh_(c);
        Ax[((size_t)(s + 1) * 2 + mt) * 16384 + hpos] = f2bf(hv);

        // ---- grid barrier (release h writes, acquire others') ----
        __threadfence();
        __syncthreads();
        if (tid == 0) {
            int old = __hip_atomic_fetch_add(&bar[0], 1, __ATOMIC_ACQ_REL,
                                             __HIP_MEMORY_SCOPE_AGENT);
            if (old == 255) {              // last of 256 blocks
                __hip_atomic_store(&bar[0], 0, __ATOMIC_RELAXED,
                                   __HIP_MEMORY_SCOPE_AGENT);
                __hip_atomic_fetch_add(&bar[32], 1, __ATOMIC_RELEASE,
                                       __HIP_MEMORY_SCOPE_AGENT);
            } else {
                while (__hip_atomic_load(&bar[32], __ATOMIC_ACQUIRE,
                                         __HIP_MEMORY_SCOPE_AGENT) <= s)
                    __builtin_amdgcn_s_sleep(1);
            }
        }
        __syncthreads();
        __threadfence();
    }
}

// ---------------------------------------------------------------------------
// mid = relu(feat @ Wnl^T + bnl). A-frags read directly from Ax/Az (global),
// B-frags from Bf2 (global). No LDS, no syncthreads -> free pipelining.
// grid (16 nb, 128 mb), 256 thr: wave w owns m-tiles mb*8+w*2, +1 (32 rows),
// 4 n-tiles of nb (64 cols).
__global__ __launch_bounds__(256) void k_gemm1(
        const u16* __restrict__ Ax, const u16* __restrict__ Az,
        const u16* __restrict__ Bf2, const float* __restrict__ bnl,
        u16* __restrict__ mid) {
    int tid = threadIdx.x;
    int nb = blockIdx.x;                  // [0,16)
    int mb = blockIdx.y;                  // [0,128)
    int w = tid >> 6, L = tid & 63;
    int lm = L & 15, quad = L >> 4;
    int mti0 = mb * 8 + w * 2;            // even -> mt=0 ; mti0+1 -> mt=1
    const u16* a0p = Ax + ((size_t)mti0 + 2) * 16384 + L * 8;
    const u16* a1p = a0p + 16384;
    const u16* az0 = Az + L * 8;
    const u16* az1 = az0 + 4096;
    const u16* bp = Bf2 + (size_t)(nb * 4) * 40 * 512 + L * 8;

    f32x4 acc[2][4];
    #pragma unroll
    for (int a = 0; a < 2; ++a)
        #pragma unroll
        for (int n = 0; n < 4; ++n) acc[a][n] = (f32x4){0.f, 0.f, 0.f, 0.f};

    #pragma unroll 4
    for (int kc = 0; kc < 32; ++kc) {
        s16x8 a0 = *reinterpret_cast<const s16x8*>(a0p + kc * 512);
        s16x8 a1 = *reinterpret_cast<const s16x8*>(a1p + kc * 512);
        #pragma unroll
        for (int n4 = 0; n4 < 4; ++n4) {
            s16x8 bv = *reinterpret_cast<const s16x8*>(bp + ((size_t)n4 * 40 + kc) * 512);
            acc[0][n4] = __builtin_amdgcn_mfma_f32_16x16x32_bf16(a0, bv, acc[0][n4], 0, 0, 0);
            acc[1][n4] = __builtin_amdgcn_mfma_f32_16x16x32_bf16(a1, bv, acc[1][n4], 0, 0, 0);
        }
    }
    #pragma unroll
    for (int kc2 = 0; kc2 < 8; ++kc2) {
        s16x8 a0 = *reinterpret_cast<const s16x8*>(az0 + kc2 * 512);
        s16x8 a1 = *reinterpret_cast<const s16x8*>(az1 + kc2 * 512);
        #pragma unroll
        for (int n4 = 0; n4 < 4; ++n4) {
            s16x8 bv = *reinterpret_cast<const s16x8*>(bp + ((size_t)n4 * 40 + 32 + kc2) * 512);
            acc[0][n4] = __builtin_amdgcn_mfma_f32_16x16x32_bf16(a0, bv, acc[0][n4], 0, 0, 0);
            acc[1][n4] = __builtin_amdgcn_mfma_f32_16x16x32_bf16(a1, bv, acc[1][n4], 0, 0, 0);
        }
    }
    #pragma unroll
    for (int mt2 = 0; mt2 < 2; ++mt2)
        #pragma unroll
        for (int n4 = 0; n4 < 4; ++n4)
            #pragma unroll
            for (int r = 0; r < 4; ++r) {
                int m = mb * 128 + w * 32 + mt2 * 16 + quad * 4 + r;
                int n = (nb * 4 + n4) * 16 + lm;
                float v = acc[mt2][n4][r] + bnl[n];
                mid[(size_t)m * H_ + n] = f2bf(fmaxf(v, 0.f));
            }
}

// ---------------------------------------------------------------------------
// logits = mid@Wout^T + bout (V=13); nll = lse - logit[label]; masked atomic acc
__global__ __launch_bounds__(256) void k_loss(
        const u16* __restrict__ mid, const float* __restrict__ Wout,
        const float* __restrict__ bout, const int* __restrict__ labels,
        const int* __restrict__ lengths, float* __restrict__ out) {
    int mrow = blockIdx.x;                // [0,16384) ; m = t*32 + b
    int b = mrow & 31, t = mrow >> 5;
    if (t >= lengths[b]) return;
    int tid = threadIdx.x;
    float p[V_];
    #pragma unroll
    for (int v = 0; v < V_; ++v) p[v] = 0.f;
    uint2 raw = *reinterpret_cast<const uint2*>(mid + (size_t)mrow * H_ + tid * 4);
    const u16* rs = (const u16*)&raw;
    float mv0 = bf2f(rs[0]), mv1 = bf2f(rs[1]), mv2 = bf2f(rs[2]), mv3 = bf2f(rs[3]);
    #pragma unroll
    for (int v = 0; v < V_; ++v) {
        float4 wv = *reinterpret_cast<const float4*>(Wout + v * H_ + tid * 4);
        p[v] = mv0 * wv.x + mv1 * wv.y + mv2 * wv.z + mv3 * wv.w;
    }
    #pragma unroll
    for (int off = 32; off > 0; off >>= 1)
        #pragma unroll
        for (int v = 0; v < V_; ++v) p[v] += __shfl_down(p[v], off);
    __shared__ float red[4][V_];
    int w = tid >> 6, L = tid & 63;
    if (L == 0)
        #pragma unroll
        for (int v = 0; v < V_; ++v) red[w][v] = p[v];
    __syncthreads();
    if (tid == 0) {
        float lg[V_]; float mx = -1e30f;
        #pragma unroll
        for (int v = 0; v < V_; ++v) {
            lg[v] = red[0][v] + red[1][v] + red[2][v] + red[3][v] + bout[v];
            mx = fmaxf(mx, lg[v]);
        }
        float se = 0.f;
        #pragma unroll
        for (int v = 0; v < V_; ++v) se += __expf(lg[v] - mx);
        float lse = mx + logf(se);
        int lab = labels[b * T_ + t];
        atomicAdd(&out[1 + b], lse - lg[lab]);
    }
}

__global__ void k_final(float* __restrict__ out) {
    float s = 0.f;
    for (int b = 0; b < B_; ++b) s += out[1 + b];
    out[0] = s;
}

// ---------------------------------------------------------------------------
extern "C" void kernel_launch(void* const* d_in, const int* in_sizes, int n_in,
                              void* d_out, int out_size, void* d_ws, size_t ws_size,
                              hipStream_t stream) {
    const float* seq    = (const float*)d_in[0];
    const float* latent = (const float*)d_in[1];
    const int*   labels = (const int*)d_in[2];
    const int*   lengths= (const int*)d_in[3];
    const float* W_ih   = (const float*)d_in[4];
    const float* W_hh   = (const float*)d_in[5];
    const float* b_ih   = (const float*)d_in[6];
    const float* b_hh   = (const float*)d_in[7];
    const float* Wz     = (const float*)d_in[8];
    const float* bz     = (const float*)d_in[9];
    const float* Wnl    = (const float*)d_in[10];
    const float* bnl    = (const float*)d_in[11];
    const float* Wout   = (const float*)d_in[12];
    const float* bout   = (const float*)d_in[13];

    char* ws = (char*)d_ws;
    u16*   Ax   = (u16*)(ws);
    u16*   Bf   = (u16*)(ws + OFF_BF);
    u16*   Bf2  = (u16*)(ws + OFF_BF2);
    float* bias = (float*)(ws + OFF_BIAS);
    u16*   Az   = (u16*)(ws + OFF_AZ);
    int*   bar  = (int*)(ws + OFF_BAR);
    u16*   mid  = (u16*)(ws + OFF_MID);
    float* out  = (float*)d_out;

    hipMemsetAsync(d_out, 0, 33 * sizeof(float), stream);
    k_init_misc<<<128, 256, 0, stream>>>(latent, Wz, bz, b_ih, b_hh, Ax, bias, Az, bar);
    k_init_wfrag<<<2048, 256, 0, stream>>>(W_hh, Bf);
    k_init_wfrag2<<<2048, 256, 0, stream>>>(Wnl, Bf2);
    k_recur<<<256, 128, 0, stream>>>(seq, W_ih, bias, Bf, Ax, bar);
    k_gemm1<<<dim3(16, 128), 256, 0, stream>>>(Ax, Az, Bf2, bnl, mid);
    k_loss<<<16384, 256, 0, stream>>>(mid, Wout, bout, labels, lengths, out);
    k_final<<<1, 1, 0, stream>>>(out);
}

// Round 3
// 3213.985 us; speedup vs baseline: 4.8009x; 4.8009x over previous
//
#include <hip/hip_runtime.h>
#include <hip/hip_bf16.h>

#define B_   32
#define T_   512
#define H_   1024
#define L_   256
#define V_   13
#define G4H  4096
#define KHL  1280   // H + L

typedef float f32x4 __attribute__((ext_vector_type(4)));
typedef short s16x8 __attribute__((ext_vector_type(8)));
typedef unsigned short u16;
typedef unsigned int   u32;

// ---------------- ws layout (bytes) ----------------
// Ax  : u16 [1026][16384]    @ 0           (33,619,968)  h chain, MFMA A-frag
// Bf  : u16 [4,194,304]      @ 33,619,968  (8,388,608)   W_hh B-fragments
// Bf2 : u16 [1,310,720]      @ 42,008,576  (2,621,440)   Wnl  B-fragments
// Az  : u16 [2][4096]        @ 44,630,016  (16,384)      latent A-frag
// bar : int [128]            @ 44,646,400  (512)         2 group counters
// mid : u16 [16384][1024]    @ 44,646,912  (33,554,432)
//   Gx (f32[57344]) and tok (u16[16384]) OVERLAY mid's space: they are only
//   read during k_recur; mid is written by k_gemm1 strictly afterwards.
#define OFF_BF   33619968u
#define OFF_BF2  42008576u
#define OFF_AZ   44630016u
#define OFF_BAR  44646400u
#define OFF_MID  44646912u
#define OFF_GX   OFF_MID                  // 229,376 B
#define OFF_TOK  (OFF_MID + 229376u)      //  32,768 B

__device__ __forceinline__ u16 f2bf(float f) {
    union { float f; u32 u; } v; v.f = f;
    u32 u = v.u;
    u32 r = (u + 0x7fffu + ((u >> 16) & 1u)) >> 16;   // RNE
    return (u16)r;
}
__device__ __forceinline__ float bf2f(u16 h) {
    union { u32 u; float f; } v; v.u = ((u32)h) << 16;
    return v.f;
}
__device__ __forceinline__ float sigm_(float x) {
    x = fminf(fmaxf(x, -30.f), 30.f);
    return 1.f / (1.f + __expf(-x));
}
__device__ __forceinline__ float tanh_(float x) {
    x = fminf(fmaxf(x, -15.f), 15.f);
    float e = __expf(2.f * x);
    return (e - 1.f) / (e + 1.f);
}

// A-frag position of (b_local, k) within a 16384-u16 slab
__device__ __forceinline__ u32 afrag_pos(int bl, int k) {
    return (u32)((k >> 5) * 512 + ((bl | (((k >> 3) & 3) << 4)) << 3) + (k & 7));
}

// ---------------------------------------------------------------------------
__global__ __launch_bounds__(256) void k_init_misc(
        const float* __restrict__ latent, const float* __restrict__ Wz,
        const float* __restrict__ bz,
        u16* __restrict__ Ax, u16* __restrict__ Az, int* __restrict__ bar) {
    int gid = blockIdx.x * 256 + threadIdx.x;          // [0, 32768)
    int b = gid >> 10, j = gid & 1023;
    const float* lrow = latent + b * L_;
    const float* wrow = Wz + j * L_;
    float acc = bz[j];
    #pragma unroll 4
    for (int l = 0; l < L_; ++l) acc += lrow[l] * wrow[l];
    Ax[(b >> 4) * 16384 + afrag_pos(b & 15, j)] = f2bf(fmaxf(acc, 0.f));
    if (gid < B_ * L_) {
        int bb = gid >> 8, l = gid & 255;
        Az[(bb >> 4) * 4096 + afrag_pos(bb & 15, l)] = f2bf(latent[gid]);
    }
    if (gid == 0) { bar[0] = 0; bar[64] = 0; }
}

// Gx[jg][gg][14]: W_ih[row][tok] + b_ih[row] + b_hh[row]; col 13 = bias only
__global__ __launch_bounds__(256) void k_init_gx(
        const float* __restrict__ W_ih, const float* __restrict__ b_ih,
        const float* __restrict__ b_hh, float* __restrict__ Gx) {
    int row = blockIdx.x * 256 + threadIdx.x;          // [0,4096)
    if (row >= G4H) return;
    int gg = row >> 10, jg = row & 1023;
    float base = b_ih[row] + b_hh[row];
    float* d = Gx + ((size_t)jg * 4 + gg) * 14;
    const float* wr = W_ih + (size_t)row * V_;
    #pragma unroll
    for (int t = 0; t < V_; ++t) d[t] = base + wr[t];
    d[13] = base;
}

// tok[s*32+b] = one-hot index of seq[b,s,:] (13 if all-zero start row)
__global__ __launch_bounds__(256) void k_init_tok(
        const float* __restrict__ seq, u16* __restrict__ tok) {
    int gid = blockIdx.x * 256 + threadIdx.x;          // [0,16384)
    int s = gid >> 5, b = gid & 31;
    const float* r = seq + ((size_t)b * T_ + s) * V_;
    int t = 13;
    #pragma unroll
    for (int v = 0; v < V_; ++v) if (r[v] > 0.5f) t = v;
    tok[gid] = (u16)t;
}

// W_hh -> MFMA B fragments, column-interleaved (4 gates x 4 j per 16-tile)
__global__ __launch_bounds__(256) void k_init_wfrag(
        const float* __restrict__ W_hh, u16* __restrict__ Bf) {
    int base = blockIdx.x * 256 + threadIdx.x;         // 2048 blocks
    #pragma unroll
    for (int i = 0; i < 8; ++i) {
        int idx = base + i * 524288;                   // [0, 4194304)
        int jv   = idx & 7;
        int lane = (idx >> 3) & 63;
        int kc   = (idx >> 9) & 31;
        int nt   = idx >> 14;
        int u = lane & 15;
        int row = (u >> 2) * H_ + nt * 4 + (u & 3);
        int k = kc * 32 + (lane >> 4) * 8 + jv;
        Bf[idx] = f2bf(W_hh[row * H_ + k]);
    }
}

__global__ __launch_bounds__(256) void k_init_wfrag2(
        const float* __restrict__ Wnl, u16* __restrict__ Bf2) {
    int idx = blockIdx.x * 256 + threadIdx.x;
    for (; idx < 1310720; idx += 524288) {
        int jv   = idx & 7;
        int lane = (idx >> 3) & 63;
        int q    = idx >> 9;                           // nt2*40 + kc
        int kc   = q % 40;
        int nt2  = q / 40;
        int n = nt2 * 16 + (lane & 15);
        int k = kc * 32 + (lane >> 4) * 8 + jv;
        Bf2[idx] = f2bf(Wnl[n * KHL + k]);
    }
}

// ---------------------------------------------------------------------------
// Persistent LSTM recurrence. 64 blocks x 512 thr (8 waves). mt = bid&1 picks
// the 16-batch group; the two groups are fully independent (own counter).
// Cross-block exchange ONLY via relaxed agent-scope atomics (LLC-coherent,
// no fences, no L2 wbinv). Barrier = monotone fetch_add counter.
__global__ __launch_bounds__(512, 2) void k_recur(
        const u16* __restrict__ tokbuf, const float* __restrict__ Gx,
        const u16* __restrict__ Bf, u16* __restrict__ Ax,
        int* __restrict__ bar) {
    __shared__ u32 AhD[8192];             // 32 KB A-frag slab
    __shared__ float scr[8][16][17];
    int tid = threadIdx.x;
    int bid = blockIdx.x;
    int mt = bid & 1;
    int w = tid >> 6, L = tid & 63;
    int nt = (bid >> 1) * 8 + w;          // [0,256)
    int lm = L & 15, quad = L >> 4;

    // one-time: B-fragments into registers (128 VGPR) — no fences in the
    // loop below, so these stay live.
    s16x8 bfr[32];
    {
        const u16* bfp = Bf + (size_t)nt * 16384 + L * 8;
        #pragma unroll
        for (int kc = 0; kc < 32; ++kc)
            bfr[kc] = *reinterpret_cast<const s16x8*>(bfp + kc * 512);
    }
    int jj = quad;
    int jg = nt * 4 + jj;
    int b = mt * 16 + lm;
    const float* gxp = Gx + (size_t)jg * 56;          // [jg][gg][14]
    u32 posu16 = (u32)((nt >> 3) * 512 + ((lm | (((nt >> 1) & 3) << 4)) << 3)
                       + (nt & 1) * 4 + quad);
    int* cnt = bar + mt * 64;             // separate cache lines per group
    u32* AxD = (u32*)Ax;
    float c = 0.f;

    for (int s = 0; s < T_; ++s) {
        // stage slab s (this mt) from LLC — coherent dword loads bypass L1/L2
        const u32* src = AxD + ((size_t)s * 2 + mt) * 8192;
        #pragma unroll
        for (int k = 0; k < 16; ++k)
            AhD[k * 512 + tid] = __hip_atomic_load(src + k * 512 + tid,
                __ATOMIC_RELAXED, __HIP_MEMORY_SCOPE_AGENT);
        __syncthreads();

        // 16x16 gates tile, K=1024 (two interleaved acc chains)
        f32x4 acc0 = {0.f, 0.f, 0.f, 0.f}, acc1 = {0.f, 0.f, 0.f, 0.f};
        const u16* ap = (const u16*)AhD + L * 8;
        #pragma unroll
        for (int kc = 0; kc < 32; kc += 2) {
            s16x8 a0 = *reinterpret_cast<const s16x8*>(ap + kc * 512);
            s16x8 a1 = *reinterpret_cast<const s16x8*>(ap + (kc + 1) * 512);
            acc0 = __builtin_amdgcn_mfma_f32_16x16x32_bf16(a0, bfr[kc], acc0, 0, 0, 0);
            acc1 = __builtin_amdgcn_mfma_f32_16x16x32_bf16(a1, bfr[kc + 1], acc1, 0, 0, 0);
        }
        #pragma unroll
        for (int r = 0; r < 4; ++r) scr[w][lm][quad * 4 + r] = acc0[r] + acc1[r];
        __syncthreads();

        // update for (b, jg)
        int tok = tokbuf[s * 32 + b];
        float g[4];
        #pragma unroll
        for (int gg = 0; gg < 4; ++gg)
            g[gg] = scr[w][gg * 4 + jj][lm] + gxp[gg * 14 + tok];
        float ig = sigm_(g[0]), fg = sigm_(g[1]);
        float gt = tanh_(g[2]), og = sigm_(g[3]);
        c = fg * c + ig * gt;
        float hv = og * tanh_(c);

        // write h(s+1): pack 2 bf16 per dword, relaxed agent store -> LLC
        u32 bits = (u32)f2bf(hv);
        u32 other = (u32)(u16)__shfl_xor((int)bits, 16);
        if (!(quad & 1)) {
            u32 word = bits | (other << 16);
            __hip_atomic_store(
                AxD + ((size_t)(s + 1) * 2 + mt) * 8192 + (posu16 >> 1),
                word, __ATOMIC_RELAXED, __HIP_MEMORY_SCOPE_AGENT);
        }
        __syncthreads();                  // drains vmcnt of every wave

        // monotone group barrier (32 blocks): no reset, no sense, no fences
        if (tid == 0) {
            int old = __hip_atomic_fetch_add(cnt, 1, __ATOMIC_RELAXED,
                                             __HIP_MEMORY_SCOPE_AGENT);
            if (old + 1 < 32 * (s + 1)) {
                while (__hip_atomic_load(cnt, __ATOMIC_RELAXED,
                                         __HIP_MEMORY_SCOPE_AGENT) < 32 * (s + 1))
                    __builtin_amdgcn_s_sleep(1);
            }
        }
        __syncthreads();
        asm volatile("" ::: "memory");    // compiler-only ordering guard
    }
}

// ---------------------------------------------------------------------------
// mid = relu(feat @ Wnl^T + bnl) — A/B frags straight from global, no LDS.
__global__ __launch_bounds__(256) void k_gemm1(
        const u16* __restrict__ Ax, const u16* __restrict__ Az,
        const u16* __restrict__ Bf2, const float* __restrict__ bnl,
        u16* __restrict__ mid) {
    int tid = threadIdx.x;
    int nb = blockIdx.x;                  // [0,16)
    int mb = blockIdx.y;                  // [0,128)
    int w = tid >> 6, L = tid & 63;
    int lm = L & 15, quad = L >> 4;
    int mti0 = mb * 8 + w * 2;
    const u16* a0p = Ax + ((size_t)mti0 + 2) * 16384 + L * 8;
    const u16* a1p = a0p + 16384;
    const u16* az0 = Az + L * 8;
    const u16* az1 = az0 + 4096;
    const u16* bp = Bf2 + (size_t)(nb * 4) * 40 * 512 + L * 8;

    f32x4 acc[2][4];
    #pragma unroll
    for (int a = 0; a < 2; ++a)
        #pragma unroll
        for (int n = 0; n < 4; ++n) acc[a][n] = (f32x4){0.f, 0.f, 0.f, 0.f};

    #pragma unroll 4
    for (int kc = 0; kc < 32; ++kc) {
        s16x8 a0 = *reinterpret_cast<const s16x8*>(a0p + kc * 512);
        s16x8 a1 = *reinterpret_cast<const s16x8*>(a1p + kc * 512);
        #pragma unroll
        for (int n4 = 0; n4 < 4; ++n4) {
            s16x8 bv = *reinterpret_cast<const s16x8*>(bp + ((size_t)n4 * 40 + kc) * 512);
            acc[0][n4] = __builtin_amdgcn_mfma_f32_16x16x32_bf16(a0, bv, acc[0][n4], 0, 0, 0);
            acc[1][n4] = __builtin_amdgcn_mfma_f32_16x16x32_bf16(a1, bv, acc[1][n4], 0, 0, 0);
        }
    }
    #pragma unroll
    for (int kc2 = 0; kc2 < 8; ++kc2) {
        s16x8 a0 = *reinterpret_cast<const s16x8*>(az0 + kc2 * 512);
        s16x8 a1 = *reinterpret_cast<const s16x8*>(az1 + kc2 * 512);
        #pragma unroll
        for (int n4 = 0; n4 < 4; ++n4) {
            s16x8 bv = *reinterpret_cast<const s16x8*>(bp + ((size_t)n4 * 40 + 32 + kc2) * 512);
            acc[0][n4] = __builtin_amdgcn_mfma_f32_16x16x32_bf16(a0, bv, acc[0][n4], 0, 0, 0);
            acc[1][n4] = __builtin_amdgcn_mfma_f32_16x16x32_bf16(a1, bv, acc[1][n4], 0, 0, 0);
        }
    }
    #pragma unroll
    for (int mt2 = 0; mt2 < 2; ++mt2)
        #pragma unroll
        for (int n4 = 0; n4 < 4; ++n4)
            #pragma unroll
            for (int r = 0; r < 4; ++r) {
                int m = mb * 128 + w * 32 + mt2 * 16 + quad * 4 + r;
                int n = (nb * 4 + n4) * 16 + lm;
                float v = acc[mt2][n4][r] + bnl[n];
                mid[(size_t)m * H_ + n] = f2bf(fmaxf(v, 0.f));
            }
}

// ---------------------------------------------------------------------------
__global__ __launch_bounds__(256) void k_loss(
        const u16* __restrict__ mid, const float* __restrict__ Wout,
        const float* __restrict__ bout, const int* __restrict__ labels,
        const int* __restrict__ lengths, float* __restrict__ out) {
    int mrow = blockIdx.x;                // m = t*32 + b
    int b = mrow & 31, t = mrow >> 5;
    if (t >= lengths[b]) return;
    int tid = threadIdx.x;
    float p[V_];
    #pragma unroll
    for (int v = 0; v < V_; ++v) p[v] = 0.f;
    uint2 raw = *reinterpret_cast<const uint2*>(mid + (size_t)mrow * H_ + tid * 4);
    const u16* rs = (const u16*)&raw;
    float mv0 = bf2f(rs[0]), mv1 = bf2f(rs[1]), mv2 = bf2f(rs[2]), mv3 = bf2f(rs[3]);
    #pragma unroll
    for (int v = 0; v < V_; ++v) {
        float4 wv = *reinterpret_cast<const float4*>(Wout + v * H_ + tid * 4);
        p[v] = mv0 * wv.x + mv1 * wv.y + mv2 * wv.z + mv3 * wv.w;
    }
    #pragma unroll
    for (int off = 32; off > 0; off >>= 1)
        #pragma unroll
        for (int v = 0; v < V_; ++v) p[v] += __shfl_down(p[v], off);
    __shared__ float red[4][V_];
    int w = tid >> 6, L = tid & 63;
    if (L == 0)
        #pragma unroll
        for (int v = 0; v < V_; ++v) red[w][v] = p[v];
    __syncthreads();
    if (tid == 0) {
        float lg[V_]; float mx = -1e30f;
        #pragma unroll
        for (int v = 0; v < V_; ++v) {
            lg[v] = red[0][v] + red[1][v] + red[2][v] + red[3][v] + bout[v];
            mx = fmaxf(mx, lg[v]);
        }
        float se = 0.f;
        #pragma unroll
        for (int v = 0; v < V_; ++v) se += __expf(lg[v] - mx);
        float lse = mx + logf(se);
        int lab = labels[b * T_ + t];
        atomicAdd(&out[1 + b], lse - lg[lab]);
    }
}

__global__ void k_final(float* __restrict__ out) {
    float s = 0.f;
    for (int b = 0; b < B_; ++b) s += out[1 + b];
    out[0] = s;
}

// ---------------------------------------------------------------------------
extern "C" void kernel_launch(void* const* d_in, const int* in_sizes, int n_in,
                              void* d_out, int out_size, void* d_ws, size_t ws_size,
                              hipStream_t stream) {
    const float* seq    = (const float*)d_in[0];
    const float* latent = (const float*)d_in[1];
    const int*   labels = (const int*)d_in[2];
    const int*   lengths= (const int*)d_in[3];
    const float* W_ih   = (const float*)d_in[4];
    const float* W_hh   = (const float*)d_in[5];
    const float* b_ih   = (const float*)d_in[6];
    const float* b_hh   = (const float*)d_in[7];
    const float* Wz     = (const float*)d_in[8];
    const float* bz     = (const float*)d_in[9];
    const float* Wnl    = (const float*)d_in[10];
    const float* bnl    = (const float*)d_in[11];
    const float* Wout   = (const float*)d_in[12];
    const float* bout   = (const float*)d_in[13];

    char* ws = (char*)d_ws;
    u16*   Ax   = (u16*)(ws);
    u16*   Bf   = (u16*)(ws + OFF_BF);
    u16*   Bf2  = (u16*)(ws + OFF_BF2);
    u16*   Az   = (u16*)(ws + OFF_AZ);
    int*   bar  = (int*)(ws + OFF_BAR);
    u16*   mid  = (u16*)(ws + OFF_MID);
    float* Gx   = (float*)(ws + OFF_GX);
    u16*   tok  = (u16*)(ws + OFF_TOK);
    float* out  = (float*)d_out;

    hipMemsetAsync(d_out, 0, 33 * sizeof(float), stream);
    k_init_misc<<<128, 256, 0, stream>>>(latent, Wz, bz, Ax, Az, bar);
    k_init_gx<<<16, 256, 0, stream>>>(W_ih, b_ih, b_hh, Gx);
    k_init_tok<<<64, 256, 0, stream>>>(seq, tok);
    k_init_wfrag<<<2048, 256, 0, stream>>>(W_hh, Bf);
    k_init_wfrag2<<<2048, 256, 0, stream>>>(Wnl, Bf2);
    k_recur<<<64, 512, 0, stream>>>(tok, Gx, Bf, Ax, bar);
    k_gemm1<<<dim3(16, 128), 256, 0, stream>>>(Ax, Az, Bf2, bnl, mid);
    k_loss<<<16384, 256, 0, stream>>>(mid, Wout, bout, labels, lengths, out);
    k_final<<<1, 1, 0, stream>>>(out);
}